// Round 7
// baseline (560.051 us; speedup 1.0000x reference)
//
#include <hip/hip_runtime.h>
#include <stdint.h>

// BinHD: samples [8192,10000] f32 {0,1}, classes [1000,10000] f32 {0,1}
// out [8192,1000] f32 = exact Hamming distance.
// v7: barrier-free MFMA hd. pack (row-major bits) -> repack (k-major groups)
// -> hd: 64x64 tile/block, 4 waves k-split (no shared LDS, no main-loop
// barriers, loads straight from L2/L3), LDS only for the final 4-way add.
#define N_ROWS 8192
#define C_CLS  1000
#define C_PAD  1024
#define D_DIM  10000
#define W64P   160            // u64 words per packed row (pad bits are 0)
#define W32P   (W64P * 2)     // 320 u32 words per packed row
#define GS     (32 * W32P)    // k-major group stride in u32 (32 rows/group)
#define KWPW   80             // k-words per wave (W32P / 4 waves)
#define NSS    20             // supersteps per wave (KWPW / 4)

typedef int v4i  __attribute__((ext_vector_type(4)));
typedef int v16i __attribute__((ext_vector_type(16)));

// ---------------------------------------------------------------------------
// Kernel 1 (unchanged, proven, ~HBM floor): bit-pack fp32 {0,1} rows into u64
// words + per-row popcount. Fixed dim permutation identical for A and B =>
// dot invariant. Writes ALL 160 words/row + rowsum.
// ---------------------------------------------------------------------------
__global__ __launch_bounds__(256) void pack_kernel(
    const float* __restrict__ samples, const float* __restrict__ classes,
    unsigned long long* __restrict__ pA, unsigned long long* __restrict__ pB,
    uint32_t* __restrict__ rsA, uint32_t* __restrict__ rsB)
{
    int gwave = (blockIdx.x * 256 + threadIdx.x) >> 6;
    int lane  = threadIdx.x & 63;
    if (gwave >= N_ROWS + C_CLS) return;   // wave-uniform exit

    const float* src;
    unsigned long long* dst;
    uint32_t* rsw;
    if (gwave < N_ROWS) {
        src = samples + (size_t)gwave * D_DIM;
        dst = pA + (size_t)gwave * W64P;
        rsw = rsA + gwave;
    } else {
        int r = gwave - N_ROWS;
        src = classes + (size_t)r * D_DIM;
        dst = pB + (size_t)r * W64P;
        rsw = rsB + r;
    }

    uint32_t rs = 0;
    #pragma unroll 4
    for (int w = 0; w < 40; ++w) {         // 40 * 4 = 160 u64 words
        int idx = w * 256 + lane * 4;      // 16B/lane, coalesced 1KB/wave
        float4 v = make_float4(0.f, 0.f, 0.f, 0.f);
        if (idx < D_DIM) v = *(const float4*)(src + idx);   // D_DIM%4==0
        unsigned long long m0 = __ballot(v.x > 0.5f);
        unsigned long long m1 = __ballot(v.y > 0.5f);
        unsigned long long m2 = __ballot(v.z > 0.5f);
        unsigned long long m3 = __ballot(v.w > 0.5f);
        rs += (uint32_t)(__popcll(m0) + __popcll(m1) + __popcll(m2) + __popcll(m3));
        if (lane == 0) {
            uint4 p0, p1;
            p0.x = (uint32_t)m0; p0.y = (uint32_t)(m0 >> 32);
            p0.z = (uint32_t)m1; p0.w = (uint32_t)(m1 >> 32);
            p1.x = (uint32_t)m2; p1.y = (uint32_t)(m2 >> 32);
            p1.z = (uint32_t)m3; p1.w = (uint32_t)(m3 >> 32);
            *(uint4*)(dst + (size_t)w * 4)     = p0;
            *(uint4*)(dst + (size_t)w * 4 + 2) = p1;
        }
    }
    if (lane == 0) *rsw = rs;
}

// ---------------------------------------------------------------------------
// Kernel 1b: repack row-major packed bits into k-major 32-row groups:
//   dst[group][kword][row]  (kword 0..319, row 0..31)
// -> hd operand load = sgpr_base + kword*128B + lane*4B: one coalesced
//    128-B global_load_dword per K-step per stream, sequential in k.
// B padded to 1024 rows; rows >= 1000 written as zeros (contribute 0).
// Reads ~12 MB (L2/L3-resident, just written by pack), writes ~12 MB.
// Writes are fully coalesced (two 128-B segments per store instr).
// ---------------------------------------------------------------------------
__global__ __launch_bounds__(256) void repack_kernel(
    const uint32_t* __restrict__ srcA, const uint32_t* __restrict__ srcB,
    uint32_t* __restrict__ dstA, uint32_t* __restrict__ dstB)
{
    const int g  = blockIdx.x;           // 0..255 = A groups, 256..287 = B
    const int t  = threadIdx.x;
    const int r  = t & 31;               // row within group
    const int wq = t >> 5;               // word-quad selector 0..7

    const uint32_t* src;
    uint32_t* dst;
    int srow;
    bool valid;
    if (g < 256) {
        src = srcA; dst = dstA + (size_t)g * GS;
        srow = g * 32 + r; valid = true;
    } else {
        int gb = g - 256;
        src = srcB; dst = dstB + (size_t)gb * GS;
        srow = gb * 32 + r; valid = (srow < C_CLS);
    }

    #pragma unroll
    for (int i = 0; i < 10; ++i) {
        int wb = (i * 8 + wq) * 4;       // base k-word of this thread's quad
        uint4 v = make_uint4(0u, 0u, 0u, 0u);
        if (valid) v = *(const uint4*)&src[(size_t)srow * W32P + wb];
        dst[(size_t)(wb + 0) * 32 + r] = v.x;
        dst[(size_t)(wb + 1) * 32 + r] = v.y;
        dst[(size_t)(wb + 2) * 32 + r] = v.z;
        dst[(size_t)(wb + 3) * 32 + r] = v.w;
    }
}

// ---------------------------------------------------------------------------
// Kernel 2: dot01 GEMM on matrix cores, BARRIER-FREE main loop.
// Block: 256 thr = 4 waves, output tile 64x64; waves split K (80 words each)
// and share nothing until the final reduction -> fully independent waves,
// the m114 overlap regime (MFMA pipe + VALU pipe co-issue across waves).
// Per wave: 20 supersteps x {16 coalesced global_load_dword (k-major layout),
// unpack {0,1} bytes, 16 mfma_i32_32x32x32_i8}, double-buffered regs.
// Grid 128x16 = 2048 blocks; VGPR ~120 -> 4 waves/SIMD.
// Epilogue: LDS[64][65] (pad+1: conflict-free), 4 serialized adds (5 barriers
// total), coalesced 256-B row stores. dist = rsA + rsB - 2*dot (exact int).
// ---------------------------------------------------------------------------
__global__ __launch_bounds__(256) void hd_kernel(
    const uint32_t* __restrict__ Akm, const uint32_t* __restrict__ Bkm,
    const uint32_t* __restrict__ rsA, const uint32_t* __restrict__ rsB,
    float* __restrict__ out)
{
    __shared__ int red[64 * 65];

    const int tid  = threadIdx.x;
    const int w    = tid >> 6;            // wave 0..3 = k-quarter
    const int lane = tid & 63;
    const int ln   = lane & 31;
    const int h4   = (lane >> 5) * 4;     // k-half bit-shift base
    const int rt   = blockIdx.x;          // 0..127 row tile
    const int ct   = blockIdx.y;          // 0..15  col tile

    // Wave-uniform stream bases (SGPR) + one per-lane 32-bit voffset.
    const uint32_t* A0 = Akm + (size_t)(2 * rt) * GS;
    const uint32_t* A1 = A0 + GS;
    const uint32_t* B0 = Bkm + (size_t)(2 * ct) * GS;
    const uint32_t* B1 = B0 + GS;
    int o = w * (KWPW * 32) + ln;         // u32 index; k-word step = +32

    uint32_t a0w[2][4], a1w[2][4], b0w[2][4], b1w[2][4];   // staged, 2 sets

#define LOADSS(s, oo) do {                                         \
    _Pragma("unroll")                                              \
    for (int k_ = 0; k_ < 4; ++k_) {                               \
        a0w[s][k_] = A0[(oo) + k_ * 32];                           \
        a1w[s][k_] = A1[(oo) + k_ * 32];                           \
        b0w[s][k_] = B0[(oo) + k_ * 32];                           \
        b1w[s][k_] = B1[(oo) + k_ * 32];                           \
    }                                                              \
} while (0)

    // bit-word -> 16 x i8 {0,1} fragment (lane's k-half selected by h4)
#define UNP(dst, src) do {                                         \
    dst[0] = (int)(((src) >> (h4 + 0)) & 0x01010101u);             \
    dst[1] = (int)(((src) >> (h4 + 1)) & 0x01010101u);             \
    dst[2] = (int)(((src) >> (h4 + 2)) & 0x01010101u);             \
    dst[3] = (int)(((src) >> (h4 + 3)) & 0x01010101u);             \
} while (0)

    v16i acc00 = {}, acc01 = {}, acc10 = {}, acc11 = {};

    LOADSS(0, o);                          // prologue: superstep 0 in flight

    #pragma unroll 2
    for (int ss = 0; ss < NSS; ++ss) {     // cur static after unroll-2
        const int cur = ss & 1;
        if (ss + 1 < NSS) LOADSS(cur ^ 1, o + 128);   // next superstep in flight

        #pragma unroll
        for (int k = 0; k < 4; ++k) {      // one K=32 MFMA step per word
            v4i a0f, a1f, b0f, b1f;
            UNP(a0f, a0w[cur][k]); UNP(b0f, b0w[cur][k]);
            acc00 = __builtin_amdgcn_mfma_i32_32x32x32_i8(a0f, b0f, acc00, 0, 0, 0);
            UNP(b1f, b1w[cur][k]);
            acc01 = __builtin_amdgcn_mfma_i32_32x32x32_i8(a0f, b1f, acc01, 0, 0, 0);
            UNP(a1f, a1w[cur][k]);
            acc10 = __builtin_amdgcn_mfma_i32_32x32x32_i8(a1f, b0f, acc10, 0, 0, 0);
            acc11 = __builtin_amdgcn_mfma_i32_32x32x32_i8(a1f, b1f, acc11, 0, 0, 0);
        }
        o += 128;
    }
#undef LOADSS
#undef UNP

    // ---- cross-wave k-quarter reduction through LDS (pad 65: bank-free) ----
    // C/D layout (32x32): col = lane&31, row = (r&3) + 8*(r>>2) + 4*(lane>>5)
    #pragma unroll
    for (int p = 0; p < 4; ++p) {
        if (w == p) {
            #pragma unroll
            for (int r = 0; r < 16; ++r) {
                const int m = (r & 3) + 8 * (r >> 2) + h4;
                if (p == 0) {
                    red[m * 65 + ln]             = acc00[r];
                    red[m * 65 + 32 + ln]        = acc01[r];
                    red[(m + 32) * 65 + ln]      = acc10[r];
                    red[(m + 32) * 65 + 32 + ln] = acc11[r];
                } else {
                    red[m * 65 + ln]             += acc00[r];
                    red[m * 65 + 32 + ln]        += acc01[r];
                    red[(m + 32) * 65 + ln]      += acc10[r];
                    red[(m + 32) * 65 + 32 + ln] += acc11[r];
                }
            }
        }
        __syncthreads();
    }

    // ---- finalize: wave w -> rows w*16..+15, lane -> col (256-B stores) ----
    const int gcol = ct * 64 + lane;
    const uint32_t rbv = (gcol < C_CLS) ? rsB[gcol] : 0u;
    #pragma unroll
    for (int i = 0; i < 16; ++i) {
        const int row  = w * 16 + i;
        const int grow = rt * 64 + row;
        const int v    = red[row * 65 + lane];
        if (gcol < C_CLS)
            out[(size_t)grow * C_CLS + gcol] =
                (float)(int)(rsA[grow] + rbv - 2u * (uint32_t)v);
    }
}

extern "C" void kernel_launch(void* const* d_in, const int* in_sizes, int n_in,
                              void* d_out, int out_size, void* d_ws, size_t ws_size,
                              hipStream_t stream) {
    const float* samples = (const float*)d_in[0];   // [8192, 10000] f32
    const float* classes = (const float*)d_in[1];   // [1000, 10000] f32
    float* out = (float*)d_out;                     // [8192, 1000] f32

    // Workspace: row-major packed A (10.49 MB) + B (1.28 MB), k-major A
    // (10.49 MB) + B-padded (1.31 MB), rowsums. All regions we read are
    // fully written each call (pack/repack cover every word incl. pads).
    uint32_t* pArm = (uint32_t*)d_ws;                       // 8192*320 u32
    uint32_t* pBrm = pArm + (size_t)N_ROWS * W32P;          // 1000*320
    uint32_t* pAkm = pBrm + (size_t)C_CLS * W32P;           // 8192*320
    uint32_t* pBkm = pAkm + (size_t)N_ROWS * W32P;          // 1024*320
    uint32_t* rsA  = pBkm + (size_t)C_PAD * W32P;           // 8192
    uint32_t* rsB  = rsA + N_ROWS;                          // 1000

    int waves  = N_ROWS + C_CLS;
    int blocks = (waves + 3) / 4;
    pack_kernel<<<blocks, 256, 0, stream>>>(samples, classes,
        (unsigned long long*)pArm, (unsigned long long*)pBrm, rsA, rsB);

    repack_kernel<<<288, 256, 0, stream>>>(pArm, pBrm, pAkm, pBkm);

    dim3 grid(N_ROWS / 64, C_PAD / 64);       // 128 x 16 = 2048 blocks
    hd_kernel<<<grid, 256, 0, stream>>>(pAkm, pBkm, rsA, rsB, out);
}

// Round 8
// 545.324 us; speedup vs baseline: 1.0270x; 1.0270x over previous
//
#include <hip/hip_runtime.h>
#include <stdint.h>

// BinHD: samples [8192,10000] f32 {0,1}, classes [1000,10000] f32 {0,1}
// out [8192,1000] f32 = exact Hamming distance.
// v8: v4's i8-MFMA {0,1} core + round-1's PROVEN global_load_lds DMA staging
// (16B-granule XOR swizzle, measured 0 bank conflicts). Removes v4's
// reg-stage + 16 ds_write_b64/thread/chunk entirely.
#define N_ROWS 8192
#define C_CLS  1000
#define D_DIM  10000
#define W64P   160            // u64 words per packed row (pad bits are 0)
#define W32P   (W64P * 2)     // 320 u32 words per packed row
#define BKW    16             // u32 words per row per chunk (512 dims)
#define NCHUNK 20             // 20 * 16 = 320 words

typedef int v4i  __attribute__((ext_vector_type(4)));
typedef int v16i __attribute__((ext_vector_type(16)));

// ---------------------------------------------------------------------------
// Kernel 1 (unchanged, proven, ~HBM floor): bit-pack fp32 {0,1} rows into u64
// words + per-row popcount. Fixed dim permutation identical for A and B =>
// dot invariant. Writes ALL 160 words/row + rowsum -> poisoned ws regions we
// later read are fully initialized.
// ---------------------------------------------------------------------------
__global__ __launch_bounds__(256) void pack_kernel(
    const float* __restrict__ samples, const float* __restrict__ classes,
    unsigned long long* __restrict__ pA, unsigned long long* __restrict__ pB,
    uint32_t* __restrict__ rsA, uint32_t* __restrict__ rsB)
{
    int gwave = (blockIdx.x * 256 + threadIdx.x) >> 6;
    int lane  = threadIdx.x & 63;
    if (gwave >= N_ROWS + C_CLS) return;   // wave-uniform exit

    const float* src;
    unsigned long long* dst;
    uint32_t* rsw;
    if (gwave < N_ROWS) {
        src = samples + (size_t)gwave * D_DIM;
        dst = pA + (size_t)gwave * W64P;
        rsw = rsA + gwave;
    } else {
        int r = gwave - N_ROWS;
        src = classes + (size_t)r * D_DIM;
        dst = pB + (size_t)r * W64P;
        rsw = rsB + r;
    }

    uint32_t rs = 0;
    #pragma unroll 4
    for (int w = 0; w < 40; ++w) {         // 40 * 4 = 160 u64 words
        int idx = w * 256 + lane * 4;      // 16B/lane, coalesced 1KB/wave
        float4 v = make_float4(0.f, 0.f, 0.f, 0.f);
        if (idx < D_DIM) v = *(const float4*)(src + idx);   // D_DIM%4==0
        unsigned long long m0 = __ballot(v.x > 0.5f);
        unsigned long long m1 = __ballot(v.y > 0.5f);
        unsigned long long m2 = __ballot(v.z > 0.5f);
        unsigned long long m3 = __ballot(v.w > 0.5f);
        rs += (uint32_t)(__popcll(m0) + __popcll(m1) + __popcll(m2) + __popcll(m3));
        if (lane == 0) {
            uint4 p0, p1;
            p0.x = (uint32_t)m0; p0.y = (uint32_t)(m0 >> 32);
            p0.z = (uint32_t)m1; p0.w = (uint32_t)(m1 >> 32);
            p1.x = (uint32_t)m2; p1.y = (uint32_t)(m2 >> 32);
            p1.z = (uint32_t)m3; p1.w = (uint32_t)(m3 >> 32);
            *(uint4*)(dst + (size_t)w * 4)     = p0;
            *(uint4*)(dst + (size_t)w * 4 + 2) = p1;
        }
    }
    if (lane == 0) *rsw = rs;
}

// ---------------------------------------------------------------------------
// Kernel 2: dot01 GEMM on matrix cores (v_mfma_i32_32x32x32_i8, {0,1} bytes).
// Block: 256 thr (4 waves, 2x2), tile 128x128; wave tile 64x64 = 2x2 accs.
// Grid 64x8 = 512 blocks. K: 20 chunks of 512 dims.
// LDS per operand per buf: [128 rows][16 words], 16B-group g of row r stored
// at slot g ^ ((r>>3)&3)  (round-1's layout, MEASURED 0 bank conflicts).
//   staging: 4 x global_load_lds(16B)/wave/chunk; swizzle carried on the
//            per-lane GLOBAL source (each lane's 16B contiguous; rule #21
//            involution), LDS dest linear. No reg staging, no ds_writes.
//   reads:   uint4 at slot (g^sw), sw=(ln>>3)&3 -> all lanes same k-group
//            (k-aligned across rows), 2-way/bcast banks = free.
// Unpack {0,1}: reg j = (word >> (h4+j)) & 0x01010101 (2 VALU/reg).
// ONE __syncthreads per chunk; its vmcnt(0) drain is free (DMA issued one
// full compute-phase earlier). dist = rsA + rsB - 2*dot01 (exact int).
// ---------------------------------------------------------------------------
__global__ __launch_bounds__(256) void hd_kernel(
    const uint32_t* __restrict__ pA, const uint32_t* __restrict__ pB,
    const uint32_t* __restrict__ rsA, const uint32_t* __restrict__ rsB,
    float* __restrict__ out)
{
    __shared__ uint32_t As[2][128 * BKW];    // 2 x 8 KB
    __shared__ uint32_t Bs[2][128 * BKW];    // 2 x 8 KB  (total 32 KB)

    const int tid  = threadIdx.x;
    const int row0 = blockIdx.x * 128;       // 64 row tiles
    const int col0 = blockIdx.y * 128;       // 8 col tiles (1024 padded)

    const int w    = tid >> 6;               // wave 0..3
    const int lane = tid & 63;
    const int wy   = w >> 1;                 // wave row half (64 rows)
    const int wx   = w & 1;                  // wave col half (64 cols)
    const int ln   = lane & 31;              // row/col within 32-tile
    const int h4   = (lane >> 5) * 4;        // k-half shift base
    const int sw   = (ln >> 3) & 3;          // read swizzle key ((row>>3)&3)

    // Per-lane pre-swizzled DMA source pointers. Instr (w,i) stages LDS rows
    // r0=(2w+i)*16..+15: lane j -> row r0+(j>>2), 16B group j&3, source group
    // (j&3) ^ ((row>>3)&3). Dest is linear (HW requirement).
    const int jrow = lane >> 2;              // 0..15
    const int jg   = lane & 3;
    const uint32_t* gA[2];
    const uint32_t* gB[2];
    #pragma unroll
    for (int i = 0; i < 2; ++i) {
        int r   = (2 * w + i) * 16 + jrow;   // LDS row (A row / B col in tile)
        int key = (r >> 3) & 3;
        int g   = jg ^ key;
        gA[i] = pA + (size_t)(row0 + r) * W32P + g * 4;
        int c = col0 + r;
        if (c >= C_CLS) c = C_CLS - 1;       // clamped cols never stored
        gB[i] = pB + (size_t)c * W32P + g * 4;
    }

#define STAGE(ch, buf) do {                                                    \
    _Pragma("unroll")                                                          \
    for (int i = 0; i < 2; ++i) {                                              \
        __builtin_amdgcn_global_load_lds(                                      \
            (const __attribute__((address_space(1))) uint32_t*)(gA[i] + (ch) * BKW), \
            (__attribute__((address_space(3))) uint32_t*)&As[buf][(2 * w + i) * 256],\
            16, 0, 0);                                                         \
        __builtin_amdgcn_global_load_lds(                                      \
            (const __attribute__((address_space(1))) uint32_t*)(gB[i] + (ch) * BKW), \
            (__attribute__((address_space(3))) uint32_t*)&Bs[buf][(2 * w + i) * 256],\
            16, 0, 0);                                                         \
    }                                                                          \
} while (0)

    // bit-word -> 16 x i8 {0,1} fragment (lane's k-half selected by h4)
#define UNP(dst, src) do {                                         \
    dst[0] = (int)(((src) >> (h4 + 0)) & 0x01010101u);             \
    dst[1] = (int)(((src) >> (h4 + 1)) & 0x01010101u);             \
    dst[2] = (int)(((src) >> (h4 + 2)) & 0x01010101u);             \
    dst[3] = (int)(((src) >> (h4 + 3)) & 0x01010101u);             \
} while (0)

    // one K=32 step: fine UNP/MFMA interleave (indep UNPs under MFMA pipe)
#define STEP(wa0_, wa1_, wb0_, wb1_) do {                          \
    v4i a0_, a1_, b0_, b1_;                                        \
    UNP(a0_, wa0_); UNP(b0_, wb0_);                                \
    acc00 = __builtin_amdgcn_mfma_i32_32x32x32_i8(a0_, b0_, acc00, 0, 0, 0); \
    UNP(b1_, wb1_);                                                \
    acc01 = __builtin_amdgcn_mfma_i32_32x32x32_i8(a0_, b1_, acc01, 0, 0, 0); \
    UNP(a1_, wa1_);                                                \
    acc10 = __builtin_amdgcn_mfma_i32_32x32x32_i8(a1_, b0_, acc10, 0, 0, 0); \
    acc11 = __builtin_amdgcn_mfma_i32_32x32x32_i8(a1_, b1_, acc11, 0, 0, 0); \
} while (0)

    v16i acc00 = {}, acc01 = {}, acc10 = {}, acc11 = {};

    const int aoff = (wy * 64 + ln) * BKW;   // A row word base (A1 at +512)
    const int boff = (wx * 64 + ln) * BKW;   // B col word base (B1 at +512)

    STAGE(0, 0);
    __syncthreads();                         // vmcnt(0): chunk-0 DMA landed

    #pragma unroll 2
    for (int ch = 0; ch < NCHUNK; ++ch) {
        const int cur = ch & 1;
        if (ch + 1 < NCHUNK) STAGE(ch + 1, cur ^ 1);  // async, flies under compute

        const uint32_t* Ac = &As[cur][0];
        const uint32_t* Bc = &Bs[cur][0];

        #pragma unroll
        for (int g = 0; g < 4; ++g) {        // one 16B k-group = 4 K-steps
            const int so = (g ^ sw) << 2;    // swizzled slot offset (words)
            uint4 a0 = *(const uint4*)&Ac[aoff + so];
            uint4 a1 = *(const uint4*)&Ac[aoff + 512 + so];
            uint4 b0 = *(const uint4*)&Bc[boff + so];
            uint4 b1 = *(const uint4*)&Bc[boff + 512 + so];
            STEP(a0.x, a1.x, b0.x, b1.x);
            STEP(a0.y, a1.y, b0.y, b1.y);
            STEP(a0.z, a1.z, b0.z, b1.z);
            STEP(a0.w, a1.w, b0.w, b1.w);
        }

        __syncthreads();   // vmcnt(0)+lgkmcnt(0): next DMA landed, cur reads done
    }
#undef STAGE
#undef UNP
#undef STEP

    // ---- epilogue: dist = rsA + rsB - 2*dot01, exact integer -> f32.
    // C/D layout (32x32): col = lane&31, row = (r&3) + 8*(r>>2) + 4*(lane>>5)
    const int gcol0 = col0 + wx * 64 + ln;
    const int gcol1 = gcol0 + 32;
    const uint32_t rb0v = (gcol0 < C_CLS) ? rsB[gcol0] : 0u;
    const uint32_t rb1v = (gcol1 < C_CLS) ? rsB[gcol1] : 0u;
    #pragma unroll
    for (int r = 0; r < 16; ++r) {
        const int m    = (r & 3) + 8 * (r >> 2) + h4;
        const int rowa = row0 + wy * 64 + m;         // tiles (0,*)
        const int rowb = rowa + 32;                  // tiles (1,*)
        const uint32_t ra0v = rsA[rowa];
        const uint32_t ra1v = rsA[rowb];
        if (gcol0 < C_CLS) {
            out[(size_t)rowa * C_CLS + gcol0] =
                (float)(int)(ra0v + rb0v - 2u * (uint32_t)acc00[r]);
            out[(size_t)rowb * C_CLS + gcol0] =
                (float)(int)(ra1v + rb0v - 2u * (uint32_t)acc10[r]);
        }
        if (gcol1 < C_CLS) {
            out[(size_t)rowa * C_CLS + gcol1] =
                (float)(int)(ra0v + rb1v - 2u * (uint32_t)acc01[r]);
            out[(size_t)rowb * C_CLS + gcol1] =
                (float)(int)(ra1v + rb1v - 2u * (uint32_t)acc11[r]);
        }
    }
}

extern "C" void kernel_launch(void* const* d_in, const int* in_sizes, int n_in,
                              void* d_out, int out_size, void* d_ws, size_t ws_size,
                              hipStream_t stream) {
    const float* samples = (const float*)d_in[0];   // [8192, 10000] f32
    const float* classes = (const float*)d_in[1];   // [1000, 10000] f32
    float* out = (float*)d_out;                     // [8192, 1000] f32

    // Workspace: packed A (10.49 MB), packed B (1.28 MB), rowsums (36.8 KB).
    unsigned long long* pA = (unsigned long long*)d_ws;
    unsigned long long* pB = pA + (size_t)N_ROWS * W64P;
    uint32_t* rsA = (uint32_t*)(pB + (size_t)C_CLS * W64P);
    uint32_t* rsB = rsA + N_ROWS;

    int waves  = N_ROWS + C_CLS;
    int blocks = (waves + 3) / 4;
    pack_kernel<<<blocks, 256, 0, stream>>>(samples, classes, pA, pB, rsA, rsB);

    dim3 grid(N_ROWS / 128, 8);              // 512 blocks (2 per CU)
    hd_kernel<<<grid, 256, 0, stream>>>((const uint32_t*)pA, (const uint32_t*)pB,
                                        rsA, rsB, out);
}